// Round 2
// baseline (561.558 us; speedup 1.0000x reference)
//
#include <hip/hip_runtime.h>
#include <hip/hip_bf16.h>
#include <stdint.h>

typedef __bf16 bf16;
typedef __bf16 bf16x8 __attribute__((ext_vector_type(8)));
typedef float floatx4 __attribute__((ext_vector_type(4)));

#define BM 128
#define BN 128
#define BK 32

// async global->LDS, 16B per lane, dest = wave-uniform base + lane*16
__device__ __forceinline__ void async_load16(const bf16* g, bf16* s) {
    __builtin_amdgcn_global_load_lds(
        (__attribute__((address_space(1))) void*)g,
        (__attribute__((address_space(3))) void*)s,
        16, 0, 0);
}

// fp32 -> bf16 cast, 8 elements/thread. n % 8 == 0.
__global__ __launch_bounds__(256) void cast_f32_bf16(
    const float* __restrict__ in, bf16* __restrict__ out, int n)
{
    int i = (blockIdx.x * 256 + threadIdx.x) * 8;
    if (i >= n) return;
    float4 a = *(const float4*)(in + i);
    float4 b = *(const float4*)(in + i + 4);
    bf16x8 o;
    o[0] = (bf16)a.x; o[1] = (bf16)a.y; o[2] = (bf16)a.z; o[3] = (bf16)a.w;
    o[4] = (bf16)b.x; o[5] = (bf16)b.y; o[6] = (bf16)b.z; o[7] = (bf16)b.w;
    *(bf16x8*)(out + i) = o;
}

// C[m,n] = sum_k A[m,k] * Bt[n,k];  A:[M,K] bf16, Bt:[N,K] bf16, C: CT (bf16 or float)
// M%128==0, N%128==0, K%32==0 assumed.
template <typename CT>
__global__ __launch_bounds__(256) void gemm_bt(
    const bf16* __restrict__ A, const bf16* __restrict__ Bt, CT* __restrict__ C,
    int M, int N, int K)
{
    __shared__ __align__(16) bf16 As[BM * BK];
    __shared__ __align__(16) bf16 Bs[BN * BK];

    const int t  = threadIdx.x;
    const int w  = t >> 6;        // wave 0..3 (2x2 wave grid)
    const int l  = t & 63;
    const int lq = l >> 4;        // quad 0..3
    const int lm = l & 15;
    const int wm = w & 1;
    const int wn = w >> 1;

    const int mBase = blockIdx.y * BM;
    const int nBase = blockIdx.x * BN;

    // staging: thread t loads 16B; 64 rows x 64B (BK*2B) per issue
    const int rowA = t >> 2;            // 0..63
    const int kelm = (t & 3) * 8;       // bf16 element offset in k

    const bf16* gA0 = A  + (size_t)(mBase + rowA)      * K + kelm;
    const bf16* gA1 = A  + (size_t)(mBase + rowA + 64) * K + kelm;
    const bf16* gB0 = Bt + (size_t)(nBase + rowA)      * K + kelm;
    const bf16* gB1 = Bt + (size_t)(nBase + rowA + 64) * K + kelm;

    bf16* sA0 = As + w * 512;           // wave-uniform LDS bases
    bf16* sA1 = As + 2048 + w * 512;
    bf16* sB0 = Bs + w * 512;
    bf16* sB1 = Bs + 2048 + w * 512;

    // fragment base: A[m=lm][k=lq*8..+7]
    const bf16* fA = As + (size_t)(wm * 64 + lm) * BK + lq * 8;
    const bf16* fB = Bs + (size_t)(wn * 64 + lm) * BK + lq * 8;

    floatx4 acc[4][4] = {};

    for (int k0 = 0; k0 < K; k0 += BK) {
        async_load16(gA0 + k0, sA0);
        async_load16(gA1 + k0, sA1);
        async_load16(gB0 + k0, sB0);
        async_load16(gB1 + k0, sB1);
        __syncthreads();               // vmcnt(0) drain: tile ready
        bf16x8 a[4], b[4];
        #pragma unroll
        for (int i = 0; i < 4; ++i) {
            a[i] = *(const bf16x8*)(fA + i * 16 * BK);
            b[i] = *(const bf16x8*)(fB + i * 16 * BK);
        }
        #pragma unroll
        for (int i = 0; i < 4; ++i)
            #pragma unroll
            for (int j = 0; j < 4; ++j)
                acc[i][j] = __builtin_amdgcn_mfma_f32_16x16x32_bf16(a[i], b[j], acc[i][j], 0, 0, 0);
        __syncthreads();               // reads done before next stage
    }

    // C/D layout: col = lane&15, row = (lane>>4)*4 + reg
    #pragma unroll
    for (int i = 0; i < 4; ++i) {
        #pragma unroll
        for (int j = 0; j < 4; ++j) {
            #pragma unroll
            for (int r = 0; r < 4; ++r) {
                const int row = mBase + wm * 64 + i * 16 + lq * 4 + r;
                const int col = nBase + wn * 64 + j * 16 + lm;
                C[(size_t)row * N + col] = (CT)acc[i][j][r];
            }
        }
    }
}

// BCx: [8192, 6144] bf16 (cols 0:2048=B, 2048:4096=C, 4096:6144=x)
// convw: [2048, 3] fp32;  Y: [8192, 2048] bf16
// y[b,s,h] = C * (w0*Bx[s-2] + w1*Bx[s-1] + w2*Bx[s]),  Bx = B*x, causal.
__global__ __launch_bounds__(256) void conv_gate(
    const bf16* __restrict__ BCx, const float* __restrict__ convw,
    bf16* __restrict__ Y)
{
    const int tx = threadIdx.x;     // 256 threads cover 2048 h, 8 each
    const int h0 = tx * 8;
    const int bb = blockIdx.y;      // batch
    const int s0 = blockIdx.x * 32; // seq chunk

    float w0[8], w1[8], w2[8];
    #pragma unroll
    for (int j = 0; j < 8; ++j) {
        w0[j] = convw[(h0 + j) * 3 + 0];
        w1[j] = convw[(h0 + j) * 3 + 1];
        w2[j] = convw[(h0 + j) * 3 + 2];
    }

    const size_t mB = (size_t)bb * 4096;

    float bx1[8], bx2[8];
    #pragma unroll
    for (int j = 0; j < 8; ++j) { bx1[j] = 0.f; bx2[j] = 0.f; }
    if (s0 >= 2) {
        const bf16* r1 = BCx + (mB + s0 - 1) * 6144;
        const bf16* r2 = BCx + (mB + s0 - 2) * 6144;
        bf16x8 B1 = *(const bf16x8*)(r1 + h0);
        bf16x8 x1 = *(const bf16x8*)(r1 + 4096 + h0);
        bf16x8 B2 = *(const bf16x8*)(r2 + h0);
        bf16x8 x2 = *(const bf16x8*)(r2 + 4096 + h0);
        #pragma unroll
        for (int j = 0; j < 8; ++j) {
            bx1[j] = (float)B1[j] * (float)x1[j];
            bx2[j] = (float)B2[j] * (float)x2[j];
        }
    }

    for (int s = s0; s < s0 + 32; ++s) {
        const size_t m = mB + s;
        const bf16* rp = BCx + m * 6144;
        bf16x8 Bv = *(const bf16x8*)(rp + h0);
        bf16x8 Cv = *(const bf16x8*)(rp + 2048 + h0);
        bf16x8 xv = *(const bf16x8*)(rp + 4096 + h0);
        bf16x8 o;
        #pragma unroll
        for (int j = 0; j < 8; ++j) {
            float bx0 = (float)Bv[j] * (float)xv[j];
            float cv  = w0[j] * bx2[j] + w1[j] * bx1[j] + w2[j] * bx0;
            o[j] = (bf16)((float)Cv[j] * cv);
            bx2[j] = bx1[j];
            bx1[j] = bx0;
        }
        *(bf16x8*)(Y + m * 2048 + h0) = o;
    }
}

extern "C" void kernel_launch(void* const* d_in, const int* in_sizes, int n_in,
                              void* d_out, int out_size, void* d_ws, size_t ws_size,
                              hipStream_t stream) {
    const float* hidden = (const float*)d_in[0];   // [2,4096,2048] fp32
    const float* Win    = (const float*)d_in[1];   // [6144,2048]  fp32 (B^T layout)
    const float* convw  = (const float*)d_in[2];   // [2048,1,3]   fp32
    const float* Wout   = (const float*)d_in[3];   // [2048,2048]  fp32 (B^T layout)
    float* out = (float*)d_out;                    // [8192,2048]  fp32

    const int nH = 8192 * 2048;      // 16,777,216
    const int nWin = 6144 * 2048;    // 12,582,912
    const int nWout = 2048 * 2048;   //  4,194,304

    bf16* hB    = (bf16*)d_ws;                       // 32 MiB
    bf16* WinB  = hB + (size_t)nH;                   // 24 MiB
    bf16* WoutB = WinB + (size_t)nWin;               //  8 MiB
    bf16* BCx   = WoutB + (size_t)nWout;             // 96 MiB
    bf16* Y     = BCx + (size_t)8192 * 6144;         // 32 MiB  (total 192 MiB)

    cast_f32_bf16<<<nH / (256 * 8), 256, 0, stream>>>(hidden, hB, nH);
    cast_f32_bf16<<<nWin / (256 * 8), 256, 0, stream>>>(Win, WinB, nWin);
    cast_f32_bf16<<<nWout / (256 * 8), 256, 0, stream>>>(Wout, WoutB, nWout);

    gemm_bt<bf16><<<dim3(6144 / BN, 8192 / BM), dim3(256), 0, stream>>>(
        hB, WinB, BCx, 8192, 6144, 2048);
    conv_gate<<<dim3(4096 / 32, 2), dim3(256), 0, stream>>>(BCx, convw, Y);
    gemm_bt<float><<<dim3(2048 / BN, 8192 / BM), dim3(256), 0, stream>>>(
        Y, WoutB, out, 8192, 2048, 2048);
}

// Round 3
// 557.804 us; speedup vs baseline: 1.0067x; 1.0067x over previous
//
#include <hip/hip_runtime.h>
#include <hip/hip_bf16.h>
#include <stdint.h>

typedef __bf16 bf16;
typedef __bf16 bf16x8 __attribute__((ext_vector_type(8)));
typedef float floatx4 __attribute__((ext_vector_type(4)));

#define BM 128
#define BN 128
#define BK 32

// async global->LDS, 16B per lane, dest = wave-uniform base + lane*16
__device__ __forceinline__ void async_load16(const bf16* g, bf16* s) {
    __builtin_amdgcn_global_load_lds(
        (__attribute__((address_space(1))) void*)g,
        (__attribute__((address_space(3))) void*)s,
        16, 0, 0);
}

// fp32 -> bf16 cast, 8 elements/thread. n % 8 == 0.
__global__ __launch_bounds__(256) void cast_f32_bf16(
    const float* __restrict__ in, bf16* __restrict__ out, int n)
{
    int i = (blockIdx.x * 256 + threadIdx.x) * 8;
    if (i >= n) return;
    float4 a = *(const float4*)(in + i);
    float4 b = *(const float4*)(in + i + 4);
    bf16x8 o;
    o[0] = (bf16)a.x; o[1] = (bf16)a.y; o[2] = (bf16)a.z; o[3] = (bf16)a.w;
    o[4] = (bf16)b.x; o[5] = (bf16)b.y; o[6] = (bf16)b.z; o[7] = (bf16)b.w;
    *(bf16x8*)(out + i) = o;
}

// C[m,n] = sum_k A[m,k] * Bt[n,k];  A:[M,K] bf16, Bt:[N,K] bf16, C: CT.
// M%128==0, N%128==0, K%32==0 assumed.
// LDS bank-conflict fix: 16B chunks within each 64B row are XOR-swizzled,
// physical_chunk = logical_chunk ^ ((row>>1)&3). Uniform bank-group spread
// at 16/32-lane granularity (2 lanes per 4-bank group = free, m136).
template <typename CT>
__global__ __launch_bounds__(256) void gemm_bt(
    const bf16* __restrict__ A, const bf16* __restrict__ Bt, CT* __restrict__ C,
    int M, int N, int K)
{
    __shared__ __align__(16) bf16 As[BM * BK];
    __shared__ __align__(16) bf16 Bs[BN * BK];

    const int t  = threadIdx.x;
    const int w  = t >> 6;        // wave 0..3 (2x2 wave grid)
    const int l  = t & 63;
    const int lq = l >> 4;        // quad 0..3
    const int lm = l & 15;
    const int wm = w & 1;
    const int wn = w >> 1;

    const int mBase = blockIdx.y * BM;
    const int nBase = blockIdx.x * BN;

    // staging: thread t fills physical (row = t>>2, chunk = t&3); the data
    // that belongs there is logical chunk (t&3) ^ ((row>>1)&3).
    const int rowA  = t >> 2;                       // 0..63
    const int lchnk = (t & 3) ^ ((t >> 3) & 3);     // swizzled logical chunk
    const int kelm  = lchnk * 8;                    // bf16 elem offset in k
    // rows rowA and rowA+64 share (row>>1)&3 bits (64>>1 = 32 ≡ 0 mod 4).

    const bf16* gA0 = A  + (size_t)(mBase + rowA)      * K + kelm;
    const bf16* gA1 = A  + (size_t)(mBase + rowA + 64) * K + kelm;
    const bf16* gB0 = Bt + (size_t)(nBase + rowA)      * K + kelm;
    const bf16* gB1 = Bt + (size_t)(nBase + rowA + 64) * K + kelm;

    bf16* sA0 = As + w * 512;           // wave-uniform LDS bases
    bf16* sA1 = As + 2048 + w * 512;
    bf16* sB0 = Bs + w * 512;
    bf16* sB1 = Bs + 2048 + w * 512;

    // fragment read: logical chunk lq of row (wm*64 + i*16 + lm) is at
    // physical chunk lq ^ ((row>>1)&3) = lq ^ ((lm>>1)&3)  (i*16, wm*64
    // contribute 0 to (row>>1)&3). Per-lane constant across i.
    const int pcA = (lq ^ ((lm >> 1) & 3)) * 8;
    const bf16* fA = As + (size_t)(wm * 64 + lm) * BK + pcA;
    const bf16* fB = Bs + (size_t)(wn * 64 + lm) * BK + pcA;

    floatx4 acc[4][4] = {};

    for (int k0 = 0; k0 < K; k0 += BK) {
        async_load16(gA0 + k0, sA0);
        async_load16(gA1 + k0, sA1);
        async_load16(gB0 + k0, sB0);
        async_load16(gB1 + k0, sB1);
        __syncthreads();               // vmcnt(0) drain: tile ready
        bf16x8 a[4], b[4];
        #pragma unroll
        for (int i = 0; i < 4; ++i) {
            a[i] = *(const bf16x8*)(fA + i * 16 * BK);
            b[i] = *(const bf16x8*)(fB + i * 16 * BK);
        }
        #pragma unroll
        for (int i = 0; i < 4; ++i)
            #pragma unroll
            for (int j = 0; j < 4; ++j)
                acc[i][j] = __builtin_amdgcn_mfma_f32_16x16x32_bf16(a[i], b[j], acc[i][j], 0, 0, 0);
        __syncthreads();               // reads done before next stage
    }

    // C/D layout: col = lane&15, row = (lane>>4)*4 + reg
    #pragma unroll
    for (int i = 0; i < 4; ++i) {
        #pragma unroll
        for (int j = 0; j < 4; ++j) {
            #pragma unroll
            for (int r = 0; r < 4; ++r) {
                const int row = mBase + wm * 64 + i * 16 + lq * 4 + r;
                const int col = nBase + wn * 64 + j * 16 + lm;
                C[(size_t)row * N + col] = (CT)acc[i][j][r];
            }
        }
    }
}

// BCx: [8192, 6144] bf16 (cols 0:2048=B, 2048:4096=C, 4096:6144=x)
// convw: [2048, 3] fp32;  Y: [8192, 2048] bf16
// y[b,s,h] = C * (w0*Bx[s-2] + w1*Bx[s-1] + w2*Bx[s]),  Bx = B*x, causal.
__global__ __launch_bounds__(256) void conv_gate(
    const bf16* __restrict__ BCx, const float* __restrict__ convw,
    bf16* __restrict__ Y)
{
    const int tx = threadIdx.x;     // 256 threads cover 2048 h, 8 each
    const int h0 = tx * 8;
    const int bb = blockIdx.y;      // batch
    const int s0 = blockIdx.x * 32; // seq chunk

    float w0[8], w1[8], w2[8];
    #pragma unroll
    for (int j = 0; j < 8; ++j) {
        w0[j] = convw[(h0 + j) * 3 + 0];
        w1[j] = convw[(h0 + j) * 3 + 1];
        w2[j] = convw[(h0 + j) * 3 + 2];
    }

    const size_t mB = (size_t)bb * 4096;

    float bx1[8], bx2[8];
    #pragma unroll
    for (int j = 0; j < 8; ++j) { bx1[j] = 0.f; bx2[j] = 0.f; }
    if (s0 >= 2) {
        const bf16* r1 = BCx + (mB + s0 - 1) * 6144;
        const bf16* r2 = BCx + (mB + s0 - 2) * 6144;
        bf16x8 B1 = *(const bf16x8*)(r1 + h0);
        bf16x8 x1 = *(const bf16x8*)(r1 + 4096 + h0);
        bf16x8 B2 = *(const bf16x8*)(r2 + h0);
        bf16x8 x2 = *(const bf16x8*)(r2 + 4096 + h0);
        #pragma unroll
        for (int j = 0; j < 8; ++j) {
            bx1[j] = (float)B1[j] * (float)x1[j];
            bx2[j] = (float)B2[j] * (float)x2[j];
        }
    }

    for (int s = s0; s < s0 + 32; ++s) {
        const size_t m = mB + s;
        const bf16* rp = BCx + m * 6144;
        bf16x8 Bv = *(const bf16x8*)(rp + h0);
        bf16x8 Cv = *(const bf16x8*)(rp + 2048 + h0);
        bf16x8 xv = *(const bf16x8*)(rp + 4096 + h0);
        bf16x8 o;
        #pragma unroll
        for (int j = 0; j < 8; ++j) {
            float bx0 = (float)Bv[j] * (float)xv[j];
            float cv  = w0[j] * bx2[j] + w1[j] * bx1[j] + w2[j] * bx0;
            o[j] = (bf16)((float)Cv[j] * cv);
            bx2[j] = bx1[j];
            bx1[j] = bx0;
        }
        *(bf16x8*)(Y + m * 2048 + h0) = o;
    }
}

extern "C" void kernel_launch(void* const* d_in, const int* in_sizes, int n_in,
                              void* d_out, int out_size, void* d_ws, size_t ws_size,
                              hipStream_t stream) {
    const float* hidden = (const float*)d_in[0];   // [2,4096,2048] fp32
    const float* Win    = (const float*)d_in[1];   // [6144,2048]  fp32 (B^T layout)
    const float* convw  = (const float*)d_in[2];   // [2048,1,3]   fp32
    const float* Wout   = (const float*)d_in[3];   // [2048,2048]  fp32 (B^T layout)
    float* out = (float*)d_out;                    // [8192,2048]  fp32

    const int nH = 8192 * 2048;      // 16,777,216
    const int nWin = 6144 * 2048;    // 12,582,912
    const int nWout = 2048 * 2048;   //  4,194,304

    bf16* hB    = (bf16*)d_ws;                       // 32 MiB
    bf16* WinB  = hB + (size_t)nH;                   // 24 MiB
    bf16* WoutB = WinB + (size_t)nWin;               //  8 MiB
    bf16* BCx   = WoutB + (size_t)nWout;             // 96 MiB
    bf16* Y     = BCx + (size_t)8192 * 6144;         // 32 MiB  (total 192 MiB)

    cast_f32_bf16<<<nH / (256 * 8), 256, 0, stream>>>(hidden, hB, nH);
    cast_f32_bf16<<<nWin / (256 * 8), 256, 0, stream>>>(Win, WinB, nWin);
    cast_f32_bf16<<<nWout / (256 * 8), 256, 0, stream>>>(Wout, WoutB, nWout);

    gemm_bt<bf16><<<dim3(6144 / BN, 8192 / BM), dim3(256), 0, stream>>>(
        hB, WinB, BCx, 8192, 6144, 2048);
    conv_gate<<<dim3(4096 / 32, 2), dim3(256), 0, stream>>>(BCx, convw, Y);
    gemm_bt<float><<<dim3(2048 / BN, 8192 / BM), dim3(256), 0, stream>>>(
        Y, WoutB, out, 8192, 2048, 2048);
}

// Round 4
// 500.139 us; speedup vs baseline: 1.1228x; 1.1153x over previous
//
#include <hip/hip_runtime.h>
#include <hip/hip_bf16.h>
#include <stdint.h>

typedef __bf16 bf16;
typedef __bf16 bf16x8 __attribute__((ext_vector_type(8)));
typedef float floatx4 __attribute__((ext_vector_type(4)));

#define BM 128
#define BN 128
#define BK 32

// fp32 -> bf16 cast, 8 elements/thread. n % 8 == 0.
__global__ __launch_bounds__(256) void cast_f32_bf16(
    const float* __restrict__ in, bf16* __restrict__ out, int n)
{
    int i = (blockIdx.x * 256 + threadIdx.x) * 8;
    if (i >= n) return;
    float4 a = *(const float4*)(in + i);
    float4 b = *(const float4*)(in + i + 4);
    bf16x8 o;
    o[0] = (bf16)a.x; o[1] = (bf16)a.y; o[2] = (bf16)a.z; o[3] = (bf16)a.w;
    o[4] = (bf16)b.x; o[5] = (bf16)b.y; o[6] = (bf16)b.z; o[7] = (bf16)b.w;
    *(bf16x8*)(out + i) = o;
}

// C[m,n] = sum_k A[m,k] * Bt[n,k];  A:[M,K] bf16, Bt:[N,K] bf16, C: CT.
// M%128==0, N%128==0, K%32==0 assumed.
//
// Register-staged double-buffered pipeline: prefetch tile k+1 into VGPRs
// (plain global loads — they do NOT need vmcnt drain at __syncthreads,
// unlike global_load_lds), compute on LDS buf[k%2], ds_write buf[(k+1)%2],
// ONE barrier per iter. Loads stay in flight across the barrier.
// LDS 16B chunks XOR-swizzled (physical = logical ^ ((row>>1)&3)) for
// conflict-free ds_read_b128 (verified: SQ_LDS_BANK_CONFLICT = 0, R3).
template <typename CT>
__global__ __launch_bounds__(256) void gemm_bt(
    const bf16* __restrict__ A, const bf16* __restrict__ Bt, CT* __restrict__ C,
    int M, int N, int K)
{
    __shared__ __align__(16) bf16 As[2 * BM * BK];
    __shared__ __align__(16) bf16 Bs[2 * BN * BK];

    const int t  = threadIdx.x;
    const int w  = t >> 6;        // wave 0..3 (2x2 wave grid)
    const int l  = t & 63;
    const int lq = l >> 4;        // quad 0..3
    const int lm = l & 15;
    const int wm = w & 1;
    const int wn = w >> 1;

    const int mBase = blockIdx.y * BM;
    const int nBase = blockIdx.x * BN;

    // staging: thread t owns physical 16B slot t (row = t>>2, chunk = t&3);
    // the data that belongs there is logical chunk (t&3) ^ ((row>>1)&3).
    const int rowA  = t >> 2;                       // 0..63
    const int lchnk = (t & 3) ^ ((t >> 3) & 3);     // swizzled logical chunk
    const int kelm  = lchnk * 8;                    // bf16 elem offset in k
    // rows rowA and rowA+64 share (row>>1)&3 (64>>1 = 32 ≡ 0 mod 4).

    const bf16* gA0 = A  + (size_t)(mBase + rowA)      * K + kelm;
    const bf16* gA1 = A  + (size_t)(mBase + rowA + 64) * K + kelm;
    const bf16* gB0 = Bt + (size_t)(nBase + rowA)      * K + kelm;
    const bf16* gB1 = Bt + (size_t)(nBase + rowA + 64) * K + kelm;

    // staging store targets (elements); +2048 = second 64-row half,
    // +4096 (BM*BK) = second buffer.
    bf16* tA0 = As + t * 8;
    bf16* tA1 = As + 2048 + t * 8;
    bf16* tB0 = Bs + t * 8;
    bf16* tB1 = Bs + 2048 + t * 8;

    // fragment read: logical chunk lq of row lives at physical chunk
    // lq ^ ((lm>>1)&3)  (i*16, wm*64 contribute 0 mod 4 to row>>1).
    const int pcA  = (lq ^ ((lm >> 1) & 3)) * 8;
    const int fAo  = (wm * 64 + lm) * BK + pcA;
    const int fBo  = (wn * 64 + lm) * BK + pcA;

    // preload tile 0 and stage into buffer 0
    bf16x8 rA0 = *(const bf16x8*)(gA0);
    bf16x8 rA1 = *(const bf16x8*)(gA1);
    bf16x8 rB0 = *(const bf16x8*)(gB0);
    bf16x8 rB1 = *(const bf16x8*)(gB1);
    *(bf16x8*)(tA0) = rA0;
    *(bf16x8*)(tA1) = rA1;
    *(bf16x8*)(tB0) = rB0;
    *(bf16x8*)(tB1) = rB1;
    __syncthreads();

    floatx4 acc[4][4] = {};
    const int kIters = K / BK;

    for (int kk = 0; kk < kIters; ++kk) {
        const int cur = (kk & 1) * (BM * BK);
        const int nxt = ((kk + 1) & 1) * (BM * BK);
        const bool hasNext = (kk + 1 < kIters);

        // prefetch tile kk+1 into regs (issue only; vmcnt waited at ds_write)
        if (hasNext) {
            const int off = (kk + 1) * BK;
            rA0 = *(const bf16x8*)(gA0 + off);
            rA1 = *(const bf16x8*)(gA1 + off);
            rB0 = *(const bf16x8*)(gB0 + off);
            rB1 = *(const bf16x8*)(gB1 + off);
        }

        // compute on buf[cur]
        bf16x8 a[4], b[4];
        #pragma unroll
        for (int i = 0; i < 4; ++i) {
            a[i] = *(const bf16x8*)(As + cur + fAo + i * 16 * BK);
            b[i] = *(const bf16x8*)(Bs + cur + fBo + i * 16 * BK);
        }
        #pragma unroll
        for (int i = 0; i < 4; ++i)
            #pragma unroll
            for (int j = 0; j < 4; ++j)
                acc[i][j] = __builtin_amdgcn_mfma_f32_16x16x32_bf16(a[i], b[j], acc[i][j], 0, 0, 0);

        // stage tile kk+1 into buf[nxt]; one barrier covers RAW and WAR
        if (hasNext) {
            *(bf16x8*)(tA0 + nxt) = rA0;
            *(bf16x8*)(tA1 + nxt) = rA1;
            *(bf16x8*)(tB0 + nxt) = rB0;
            *(bf16x8*)(tB1 + nxt) = rB1;
            __syncthreads();
        }
    }

    // C/D layout: col = lane&15, row = (lane>>4)*4 + reg
    #pragma unroll
    for (int i = 0; i < 4; ++i) {
        #pragma unroll
        for (int j = 0; j < 4; ++j) {
            #pragma unroll
            for (int r = 0; r < 4; ++r) {
                const int row = mBase + wm * 64 + i * 16 + lq * 4 + r;
                const int col = nBase + wn * 64 + j * 16 + lm;
                C[(size_t)row * N + col] = (CT)acc[i][j][r];
            }
        }
    }
}

// BCx: [8192, 6144] bf16 (cols 0:2048=B, 2048:4096=C, 4096:6144=x)
// convw: [2048, 3] fp32;  Y: [8192, 2048] bf16
// y[b,s,h] = C * (w0*Bx[s-2] + w1*Bx[s-1] + w2*Bx[s]),  Bx = B*x, causal.
__global__ __launch_bounds__(256) void conv_gate(
    const bf16* __restrict__ BCx, const float* __restrict__ convw,
    bf16* __restrict__ Y)
{
    const int tx = threadIdx.x;     // 256 threads cover 2048 h, 8 each
    const int h0 = tx * 8;
    const int bb = blockIdx.y;      // batch
    const int s0 = blockIdx.x * 32; // seq chunk

    float w0[8], w1[8], w2[8];
    #pragma unroll
    for (int j = 0; j < 8; ++j) {
        w0[j] = convw[(h0 + j) * 3 + 0];
        w1[j] = convw[(h0 + j) * 3 + 1];
        w2[j] = convw[(h0 + j) * 3 + 2];
    }

    const size_t mB = (size_t)bb * 4096;

    float bx1[8], bx2[8];
    #pragma unroll
    for (int j = 0; j < 8; ++j) { bx1[j] = 0.f; bx2[j] = 0.f; }
    if (s0 >= 2) {
        const bf16* r1 = BCx + (mB + s0 - 1) * 6144;
        const bf16* r2 = BCx + (mB + s0 - 2) * 6144;
        bf16x8 B1 = *(const bf16x8*)(r1 + h0);
        bf16x8 x1 = *(const bf16x8*)(r1 + 4096 + h0);
        bf16x8 B2 = *(const bf16x8*)(r2 + h0);
        bf16x8 x2 = *(const bf16x8*)(r2 + 4096 + h0);
        #pragma unroll
        for (int j = 0; j < 8; ++j) {
            bx1[j] = (float)B1[j] * (float)x1[j];
            bx2[j] = (float)B2[j] * (float)x2[j];
        }
    }

    for (int s = s0; s < s0 + 32; ++s) {
        const size_t m = mB + s;
        const bf16* rp = BCx + m * 6144;
        bf16x8 Bv = *(const bf16x8*)(rp + h0);
        bf16x8 Cv = *(const bf16x8*)(rp + 2048 + h0);
        bf16x8 xv = *(const bf16x8*)(rp + 4096 + h0);
        bf16x8 o;
        #pragma unroll
        for (int j = 0; j < 8; ++j) {
            float bx0 = (float)Bv[j] * (float)xv[j];
            float cv  = w0[j] * bx2[j] + w1[j] * bx1[j] + w2[j] * bx0;
            o[j] = (bf16)((float)Cv[j] * cv);
            bx2[j] = bx1[j];
            bx1[j] = bx0;
        }
        *(bf16x8*)(Y + m * 2048 + h0) = o;
    }
}

extern "C" void kernel_launch(void* const* d_in, const int* in_sizes, int n_in,
                              void* d_out, int out_size, void* d_ws, size_t ws_size,
                              hipStream_t stream) {
    const float* hidden = (const float*)d_in[0];   // [2,4096,2048] fp32
    const float* Win    = (const float*)d_in[1];   // [6144,2048]  fp32 (B^T layout)
    const float* convw  = (const float*)d_in[2];   // [2048,1,3]   fp32
    const float* Wout   = (const float*)d_in[3];   // [2048,2048]  fp32 (B^T layout)
    float* out = (float*)d_out;                    // [8192,2048]  fp32

    const int nH = 8192 * 2048;      // 16,777,216
    const int nWin = 6144 * 2048;    // 12,582,912
    const int nWout = 2048 * 2048;   //  4,194,304

    bf16* hB    = (bf16*)d_ws;                       // 32 MiB
    bf16* WinB  = hB + (size_t)nH;                   // 24 MiB
    bf16* WoutB = WinB + (size_t)nWin;               //  8 MiB
    bf16* BCx   = WoutB + (size_t)nWout;             // 96 MiB
    bf16* Y     = BCx + (size_t)8192 * 6144;         // 32 MiB  (total 192 MiB)

    cast_f32_bf16<<<nH / (256 * 8), 256, 0, stream>>>(hidden, hB, nH);
    cast_f32_bf16<<<nWin / (256 * 8), 256, 0, stream>>>(Win, WinB, nWin);
    cast_f32_bf16<<<nWout / (256 * 8), 256, 0, stream>>>(Wout, WoutB, nWout);

    gemm_bt<bf16><<<dim3(6144 / BN, 8192 / BM), dim3(256), 0, stream>>>(
        hB, WinB, BCx, 8192, 6144, 2048);
    conv_gate<<<dim3(4096 / 32, 2), dim3(256), 0, stream>>>(BCx, convw, Y);
    gemm_bt<float><<<dim3(2048 / BN, 8192 / BM), dim3(256), 0, stream>>>(
        Y, WoutB, out, 8192, 2048, 2048);
}

// Round 5
// 464.710 us; speedup vs baseline: 1.2084x; 1.0762x over previous
//
#include <hip/hip_runtime.h>
#include <hip/hip_bf16.h>
#include <stdint.h>

typedef __bf16 bf16;
typedef __bf16 bf16x8 __attribute__((ext_vector_type(8)));
typedef float floatx4 __attribute__((ext_vector_type(4)));

#define BM 128
#define BN 256
#define BK 32

// fp32 -> bf16 cast, 8 elements/thread. n % 8 == 0.
__global__ __launch_bounds__(256) void cast_f32_bf16(
    const float* __restrict__ in, bf16* __restrict__ out, int n)
{
    int i = (blockIdx.x * 256 + threadIdx.x) * 8;
    if (i >= n) return;
    float4 a = *(const float4*)(in + i);
    float4 b = *(const float4*)(in + i + 4);
    bf16x8 o;
    o[0] = (bf16)a.x; o[1] = (bf16)a.y; o[2] = (bf16)a.z; o[3] = (bf16)a.w;
    o[4] = (bf16)b.x; o[5] = (bf16)b.y; o[6] = (bf16)b.z; o[7] = (bf16)b.w;
    *(bf16x8*)(out + i) = o;
}

// C[m,n] = sum_k A[m,k] * Bt[n,k];  A:[M,K] bf16, Bt:[N,K] bf16, C: CT.
// M%128==0, N%256==0, K%32==0 assumed.
//
// LDS-BW-bound fix (R4 analysis: 63 B/cyc/CU effective, 3x matrix pipe
// load): 64x128 wave tiles (4 waves, 128x256 block) cut LDS bytes/FLOP
// by 25% vs 64x64. Reg-staged double-buffered pipeline, ONE barrier/iter,
// plain global loads stay in flight across the barrier (R4-verified:
// VALUBusy 49->17). XOR chunk swizzle: conflict-free (R3-verified: 0).
template <typename CT>
__global__ __launch_bounds__(256, 2) void gemm_bt(
    const bf16* __restrict__ A, const bf16* __restrict__ Bt, CT* __restrict__ C,
    int M, int N, int K)
{
    __shared__ __align__(16) bf16 As[2 * BM * BK];   // 16 KB
    __shared__ __align__(16) bf16 Bs[2 * BN * BK];   // 32 KB

    const int t  = threadIdx.x;
    const int w  = t >> 6;        // wave 0..3 (2x2 grid: m=w&1, n=w>>1)
    const int l  = t & 63;
    const int lq = l >> 4;        // quad 0..3
    const int lm = l & 15;
    const int wm = w & 1;
    const int wn = w >> 1;

    const int mBase = blockIdx.y * BM;
    const int nBase = blockIdx.x * BN;

    // staging: thread t owns physical 16B slot (row = t>>2, chunk = t&3)
    // in each 64-row slab; logical chunk there = (t&3) ^ ((row>>1)&3).
    const int rowT  = t >> 2;                       // 0..63
    const int lchnk = (t & 3) ^ ((t >> 3) & 3);     // swizzled logical chunk
    const int kelm  = lchnk * 8;
    // slabs at +64 rows share (row>>1)&3 (64>>1 = 32 ≡ 0 mod 4).

    const bf16* gA0 = A  + (size_t)(mBase + rowT)       * K + kelm;
    const bf16* gA1 = A  + (size_t)(mBase + rowT + 64)  * K + kelm;
    const bf16* gB0 = Bt + (size_t)(nBase + rowT)       * K + kelm;
    const bf16* gB1 = Bt + (size_t)(nBase + rowT + 64)  * K + kelm;
    const bf16* gB2 = Bt + (size_t)(nBase + rowT + 128) * K + kelm;
    const bf16* gB3 = Bt + (size_t)(nBase + rowT + 192) * K + kelm;

    // staging store targets (elements); slab stride 2048 = 64 rows * 32.
    bf16* tA0 = As + t * 8;
    bf16* tA1 = As + 2048 + t * 8;
    bf16* tB0 = Bs + t * 8;
    bf16* tB1 = Bs + 2048 + t * 8;
    bf16* tB2 = Bs + 4096 + t * 8;
    bf16* tB3 = Bs + 6144 + t * 8;

    // fragment read: logical chunk lq of row r lives at physical chunk
    // lq ^ ((r>>1)&3); all row terms except lm are ≡ 0 mod 4 after >>1.
    const int pc  = (lq ^ ((lm >> 1) & 3)) * 8;
    const int fAo = (wm * 64 + lm) * BK + pc;
    const int fBo = (wn * 128 + lm) * BK + pc;

    // preload tile 0 and stage into buffer 0
    bf16x8 rA0 = *(const bf16x8*)(gA0);
    bf16x8 rA1 = *(const bf16x8*)(gA1);
    bf16x8 rB0 = *(const bf16x8*)(gB0);
    bf16x8 rB1 = *(const bf16x8*)(gB1);
    bf16x8 rB2 = *(const bf16x8*)(gB2);
    bf16x8 rB3 = *(const bf16x8*)(gB3);
    *(bf16x8*)(tA0) = rA0;
    *(bf16x8*)(tA1) = rA1;
    *(bf16x8*)(tB0) = rB0;
    *(bf16x8*)(tB1) = rB1;
    *(bf16x8*)(tB2) = rB2;
    *(bf16x8*)(tB3) = rB3;
    __syncthreads();

    floatx4 acc[4][8] = {};
    const int kIters = K / BK;

    for (int kk = 0; kk < kIters; ++kk) {
        const int curA = (kk & 1) * (BM * BK);
        const int curB = (kk & 1) * (BN * BK);
        const int nxtA = ((kk + 1) & 1) * (BM * BK);
        const int nxtB = ((kk + 1) & 1) * (BN * BK);
        const bool hasNext = (kk + 1 < kIters);

        // prefetch tile kk+1 into regs (issue only; waited at ds_write)
        if (hasNext) {
            const int off = (kk + 1) * BK;
            rA0 = *(const bf16x8*)(gA0 + off);
            rA1 = *(const bf16x8*)(gA1 + off);
            rB0 = *(const bf16x8*)(gB0 + off);
            rB1 = *(const bf16x8*)(gB1 + off);
            rB2 = *(const bf16x8*)(gB2 + off);
            rB3 = *(const bf16x8*)(gB3 + off);
        }

        // compute on buf[cur]
        bf16x8 a[4], b[8];
        #pragma unroll
        for (int i = 0; i < 4; ++i)
            a[i] = *(const bf16x8*)(As + curA + fAo + i * 16 * BK);
        #pragma unroll
        for (int j = 0; j < 8; ++j)
            b[j] = *(const bf16x8*)(Bs + curB + fBo + j * 16 * BK);
        #pragma unroll
        for (int i = 0; i < 4; ++i)
            #pragma unroll
            for (int j = 0; j < 8; ++j)
                acc[i][j] = __builtin_amdgcn_mfma_f32_16x16x32_bf16(a[i], b[j], acc[i][j], 0, 0, 0);

        // stage tile kk+1 into buf[nxt]; one barrier covers RAW and WAR
        if (hasNext) {
            *(bf16x8*)(tA0 + nxtA) = rA0;
            *(bf16x8*)(tA1 + nxtA) = rA1;
            *(bf16x8*)(tB0 + nxtB) = rB0;
            *(bf16x8*)(tB1 + nxtB) = rB1;
            *(bf16x8*)(tB2 + nxtB) = rB2;
            *(bf16x8*)(tB3 + nxtB) = rB3;
            __syncthreads();
        }
    }

    // C/D layout: col = lane&15, row = (lane>>4)*4 + reg
    #pragma unroll
    for (int i = 0; i < 4; ++i) {
        #pragma unroll
        for (int j = 0; j < 8; ++j) {
            #pragma unroll
            for (int r = 0; r < 4; ++r) {
                const int row = mBase + wm * 64 + i * 16 + lq * 4 + r;
                const int col = nBase + wn * 128 + j * 16 + lm;
                C[(size_t)row * N + col] = (CT)acc[i][j][r];
            }
        }
    }
}

// BCx: [8192, 6144] bf16 (cols 0:2048=B, 2048:4096=C, 4096:6144=x)
// convw: [2048, 3] fp32;  Y: [8192, 2048] bf16
// y[b,s,h] = C * (w0*Bx[s-2] + w1*Bx[s-1] + w2*Bx[s]),  Bx = B*x, causal.
__global__ __launch_bounds__(256) void conv_gate(
    const bf16* __restrict__ BCx, const float* __restrict__ convw,
    bf16* __restrict__ Y)
{
    const int tx = threadIdx.x;     // 256 threads cover 2048 h, 8 each
    const int h0 = tx * 8;
    const int bb = blockIdx.y;      // batch
    const int s0 = blockIdx.x * 32; // seq chunk

    float w0[8], w1[8], w2[8];
    #pragma unroll
    for (int j = 0; j < 8; ++j) {
        w0[j] = convw[(h0 + j) * 3 + 0];
        w1[j] = convw[(h0 + j) * 3 + 1];
        w2[j] = convw[(h0 + j) * 3 + 2];
    }

    const size_t mB = (size_t)bb * 4096;

    float bx1[8], bx2[8];
    #pragma unroll
    for (int j = 0; j < 8; ++j) { bx1[j] = 0.f; bx2[j] = 0.f; }
    if (s0 >= 2) {
        const bf16* r1 = BCx + (mB + s0 - 1) * 6144;
        const bf16* r2 = BCx + (mB + s0 - 2) * 6144;
        bf16x8 B1 = *(const bf16x8*)(r1 + h0);
        bf16x8 x1 = *(const bf16x8*)(r1 + 4096 + h0);
        bf16x8 B2 = *(const bf16x8*)(r2 + h0);
        bf16x8 x2 = *(const bf16x8*)(r2 + 4096 + h0);
        #pragma unroll
        for (int j = 0; j < 8; ++j) {
            bx1[j] = (float)B1[j] * (float)x1[j];
            bx2[j] = (float)B2[j] * (float)x2[j];
        }
    }

    for (int s = s0; s < s0 + 32; ++s) {
        const size_t m = mB + s;
        const bf16* rp = BCx + m * 6144;
        bf16x8 Bv = *(const bf16x8*)(rp + h0);
        bf16x8 Cv = *(const bf16x8*)(rp + 2048 + h0);
        bf16x8 xv = *(const bf16x8*)(rp + 4096 + h0);
        bf16x8 o;
        #pragma unroll
        for (int j = 0; j < 8; ++j) {
            float bx0 = (float)Bv[j] * (float)xv[j];
            float cv  = w0[j] * bx2[j] + w1[j] * bx1[j] + w2[j] * bx0;
            o[j] = (bf16)((float)Cv[j] * cv);
            bx2[j] = bx1[j];
            bx1[j] = bx0;
        }
        *(bf16x8*)(Y + m * 2048 + h0) = o;
    }
}

extern "C" void kernel_launch(void* const* d_in, const int* in_sizes, int n_in,
                              void* d_out, int out_size, void* d_ws, size_t ws_size,
                              hipStream_t stream) {
    const float* hidden = (const float*)d_in[0];   // [2,4096,2048] fp32
    const float* Win    = (const float*)d_in[1];   // [6144,2048]  fp32 (B^T layout)
    const float* convw  = (const float*)d_in[2];   // [2048,1,3]   fp32
    const float* Wout   = (const float*)d_in[3];   // [2048,2048]  fp32 (B^T layout)
    float* out = (float*)d_out;                    // [8192,2048]  fp32

    const int nH = 8192 * 2048;      // 16,777,216
    const int nWin = 6144 * 2048;    // 12,582,912
    const int nWout = 2048 * 2048;   //  4,194,304

    bf16* hB    = (bf16*)d_ws;                       // 32 MiB
    bf16* WinB  = hB + (size_t)nH;                   // 24 MiB
    bf16* WoutB = WinB + (size_t)nWin;               //  8 MiB
    bf16* BCx   = WoutB + (size_t)nWout;             // 96 MiB
    bf16* Y     = BCx + (size_t)8192 * 6144;         // 32 MiB  (total 192 MiB)

    cast_f32_bf16<<<nH / (256 * 8), 256, 0, stream>>>(hidden, hB, nH);
    cast_f32_bf16<<<nWin / (256 * 8), 256, 0, stream>>>(Win, WinB, nWin);
    cast_f32_bf16<<<nWout / (256 * 8), 256, 0, stream>>>(Wout, WoutB, nWout);

    gemm_bt<bf16><<<dim3(6144 / BN, 8192 / BM), dim3(256), 0, stream>>>(
        hB, WinB, BCx, 8192, 6144, 2048);
    conv_gate<<<dim3(4096 / 32, 2), dim3(256), 0, stream>>>(BCx, convw, Y);
    gemm_bt<float><<<dim3(2048 / BN, 8192 / BM), dim3(256), 0, stream>>>(
        Y, WoutB, out, 8192, 2048, 2048);
}